// Round 11
// baseline (305.163 us; speedup 1.0000x reference)
//
#include <hip/hip_runtime.h>
#include <cstdint>
#include <cstddef>

#define BB 64
#define DD 1024
#define HH 8
#define VV 32000
#define H4 4096
#define BM 256
#define BK 32
#define NBLK 125              // VV / BM

// ws layout (float offsets)
#define OFF_HHI    0            // 64*1024 f16 = 32768 floats
#define OFF_HLO    32768        // 64*1024 f16
#define OFF_R      65536        // 64*4096 f32
#define OFF_NLL    327680       // 512
#define OFF_CNT    328192       // 512
#define OFF_SCAL   328704       // 4
#define OFF_PMAX   330000       // 512*125
#define OFF_PSUM   394000       // 512*125

// d_out layout (floats)
#define OFF_LOGITS 0
#define OFF_GATE   16384000
#define OFF_ACT    16384512
#define OFF_LOSS   16385024

typedef __attribute__((ext_vector_type(8))) _Float16 f16x8;
typedef __attribute__((ext_vector_type(4))) float f32x4;

// ---------------- hidden fp32 -> f16 hi + lo ---------------------------------
__global__ void k_h2f16split(const float* __restrict__ in,
                             _Float16* __restrict__ hi_out,
                             _Float16* __restrict__ lo_out) {
    int i = blockIdx.x * 256 + threadIdx.x;   // 65536 elems
    float x = in[i];
    _Float16 hi = (_Float16)x;
    hi_out[i] = hi;
    lo_out[i] = (_Float16)(x - (float)hi);
}

// ---------------- router layer 1: r[b][j] = gelu(h @ w1^T + b1) --------------
__global__ __launch_bounds__(64) void k_router1(
    const float* __restrict__ w1, const _Float16* __restrict__ hhi,
    const _Float16* __restrict__ hlo, const float* __restrict__ b1,
    float* __restrict__ r) {
    const int j0 = blockIdx.x * 16;
    const int lane = threadIdx.x;
    const int lg = lane >> 4, lr = lane & 15;
    const float* wp = w1 + (size_t)(j0 + lr) * DD + lg * 8;

    f32x4 acc[4];
#pragma unroll
    for (int nt = 0; nt < 4; ++nt) acc[nt] = (f32x4){0.f, 0.f, 0.f, 0.f};

    for (int kc = 0; kc < DD; kc += 32) {
        float4 a0 = *(const float4*)(wp + kc);
        float4 a1 = *(const float4*)(wp + kc + 4);
        float av[8] = {a0.x, a0.y, a0.z, a0.w, a1.x, a1.y, a1.z, a1.w};
        f16x8 fahi, falo;
#pragma unroll
        for (int j = 0; j < 8; ++j) {
            _Float16 h16 = (_Float16)av[j];
            fahi[j] = h16;
            falo[j] = (_Float16)(av[j] - (float)h16);
        }
#pragma unroll
        for (int nt = 0; nt < 4; ++nt) {
            size_t boff = (size_t)(nt * 16 + lr) * DD + kc + lg * 8;
            f16x8 fbhi = *(const f16x8*)(hhi + boff);
            f16x8 fblo = *(const f16x8*)(hlo + boff);
            acc[nt] = __builtin_amdgcn_mfma_f32_16x16x32_f16(fahi, fbhi, acc[nt], 0, 0, 0);
            acc[nt] = __builtin_amdgcn_mfma_f32_16x16x32_f16(fahi, fblo, acc[nt], 0, 0, 0);
            acc[nt] = __builtin_amdgcn_mfma_f32_16x16x32_f16(falo, fbhi, acc[nt], 0, 0, 0);
        }
    }

#pragma unroll
    for (int nt = 0; nt < 4; ++nt) {
        int b = nt * 16 + lr;
        int j = j0 + lg * 4;
        float4 o;
        float* ov = (float*)&o;
#pragma unroll
        for (int q = 0; q < 4; ++q) {
            float s = acc[nt][q] + b1[j + q];
            ov[q] = 0.5f * s * (1.0f + erff(s * 0.70710678118654752f));
        }
        *(float4*)&r[(size_t)b * H4 + j] = o;
    }
}

// ---------------- router layer 2: gate[b][h] ---------------------------------
__global__ void k_router2(const float* __restrict__ r, const float* __restrict__ w2,
                          const float* __restrict__ b2, float* __restrict__ gate) {
    int b = blockIdx.x;
    int h = threadIdx.x >> 5;
    int lane = threadIdx.x & 31;
    const float* rr = r + (size_t)b * H4;
    const float* ww = w2 + (size_t)h * H4;
    float s = 0.f;
    for (int j = lane; j < H4; j += 32) s = fmaf(rr[j], ww[j], s);
    for (int off = 16; off > 0; off >>= 1) s += __shfl_down(s, off, 32);
    if (lane == 0) gate[b * HH + h] = s + b2[h];
}

// ---------------- top-k routing + BCE/LB/entropy/budget ----------------------
__global__ void k_routing_aux(const float* __restrict__ gate, const int* __restrict__ kmaxp,
                              float* __restrict__ act_out, float* __restrict__ scal) {
    __shared__ float af[64][8];
    __shared__ float bces[64], ents[64];
    int b = threadIdx.x;   // 64 threads
    float g[8];
#pragma unroll
    for (int h = 0; h < 8; ++h) g[h] = gate[b * 8 + h];
    int k = kmaxp[0]; k = k < 0 ? 0 : (k > 8 ? 8 : k);
    bool act[8] = {false, false, false, false, false, false, false, false};
    for (int s = 0; s < k; ++s) {
        int best = -1; float bv = -1e30f;
#pragma unroll
        for (int h = 0; h < 8; ++h)
            if (!act[h] && g[h] > bv) { bv = g[h]; best = h; }
        act[best] = true;
    }
    float m = -1e30f;
#pragma unroll
    for (int h = 0; h < 8; ++h) m = fmaxf(m, g[h]);
    float se = 0.f, ex[8];
#pragma unroll
    for (int h = 0; h < 8; ++h) { ex[h] = expf(g[h] - m); se += ex[h]; }
    float bce = 0.f, ent = 0.f;
#pragma unroll
    for (int h = 0; h < 8; ++h) {
        float t = act[h] ? 1.f : 0.f;
        bce += fmaxf(g[h], 0.f) - g[h] * t + log1pf(expf(-fabsf(g[h])));
        float p = ex[h] / se;
        ent -= p * logf(p + 1e-9f);
        af[b][h] = t;
        act_out[b * 8 + h] = t;
    }
    bces[b] = bce; ents[b] = ent;
    __syncthreads();
    if (b == 0) {
        float bsum = 0.f, esum = 0.f, asum = 0.f, lb = 0.f;
        for (int i = 0; i < 64; ++i) { bsum += bces[i]; esum += ents[i]; }
        for (int h = 0; h < 8; ++h) {
            float f = 0.f;
            for (int i = 0; i < 64; ++i) f += af[i][h];
            asum += f;
            float fr = f / 64.f - 0.125f;
            lb += fr * fr;
        }
        scal[0] = bsum / 512.f;   // bce mean
        scal[1] = lb;             // load balance
        scal[2] = esum / 64.f;    // entropy mean
        scal[3] = asum / 512.f;   // budget
    }
}

// ---------------- big GEMM: MFMA f16, NT stream, 32KB buffer, 4 blocks/CU ----
// R8 structure (single [32][256] buffer, serial stage->drain->compute, 4
// blocks/CU for latency coverage via inter-block desync) + NT policy on the
// 1GB W stream (R9's proven lever) + NT logits stores + fused CE partials.
__global__ __launch_bounds__(256, 4) void k_heads_gemm(
    const float* __restrict__ W, const _Float16* __restrict__ hA,
    float* __restrict__ out, float* __restrict__ pmax, float* __restrict__ psum) {
    __shared__ __align__(16) float ldsA[BK][256];   // 32 KB
    const int bid = blockIdx.x;
    const int h   = bid & 7;
    const int blk = bid >> 3;
    const int v0  = blk * BM;
    const int tid = threadIdx.x;
    const int wv = tid >> 6, lane = tid & 63;
    const int lg = lane >> 4, lr = lane & 15;

    const float* wbase = W + (size_t)h * DD * VV + v0;

    f32x4 acc[4][4];
#pragma unroll
    for (int vt = 0; vt < 4; ++vt)
#pragma unroll
        for (int nt = 0; nt < 4; ++nt) acc[vt][nt] = (f32x4){0.f, 0.f, 0.f, 0.f};

    for (int kc = 0; kc < DD / BK; ++kc) {   // 32 chunks
        // stage chunk kc: 8 gll per wave, each one full 1KB row (sigma-swizzled), NT
#pragma unroll
        for (int i_ = 0; i_ < 8; ++i_) {
            int r_ = wv + 4 * i_;
            const float* src_ = wbase + (size_t)(kc * BK + r_) * VV
                                + ((lane ^ (r_ >> 3)) << 2);
            __builtin_amdgcn_global_load_lds(
                (const __attribute__((address_space(1))) unsigned int*)src_,
                (__attribute__((address_space(3))) unsigned int*)&ldsA[r_][0],
                16, 0, 2 /* CPol NT: stream, don't allocate */);
        }
        asm volatile("s_waitcnt vmcnt(0)" ::: "memory");
        asm volatile("s_barrier" ::: "memory");

        // B-frags from global (L2/LLC-resident 128KB)
        f16x8 fb[4];
#pragma unroll
        for (int nt = 0; nt < 4; ++nt)
            fb[nt] = *(const f16x8*)(hA + (size_t)(nt * 16 + lr) * DD + kc * BK + lg * 8);

        // A-frags from LDS (sigma-swizzled columns) + MFMA
        const int vq_base = wv * 16 + (lr >> 2);
#pragma unroll
        for (int vt = 0; vt < 4; ++vt) {
            const int p = (vq_base + vt * 4) ^ lg;           // granule index
            const float* col = &ldsA[lg * 8][(p << 2) + (lr & 3)];
            f16x8 fa;
#pragma unroll
            for (int j = 0; j < 8; ++j) fa[j] = (_Float16)col[j * 256];
#pragma unroll
            for (int nt = 0; nt < 4; ++nt)
                acc[vt][nt] = __builtin_amdgcn_mfma_f32_16x16x32_f16(fa, fb[nt], acc[vt][nt], 0, 0, 0);
        }

        asm volatile("s_waitcnt lgkmcnt(0)" ::: "memory");
        asm volatile("s_barrier" ::: "memory");   // WAR: LDS reads done before restage
    }

    // ---- epilogue: two passes through 32KB LDS (b 0..31, then 32..63) -------
    float* sm = &ldsA[0][0];   // [32][256]
#pragma unroll
    for (int pass = 0; pass < 2; ++pass) {
#pragma unroll
        for (int nt2 = 0; nt2 < 2; ++nt2) {
            int nt = pass * 2 + nt2;
            int b = nt * 16 + lr;
            int brow = nt2 * 16 + lr;
#pragma unroll
            for (int vt = 0; vt < 4; ++vt) {
                int vcol = wv * 64 + vt * 16 + lg * 4;
                int col = vcol ^ ((b & 7) << 2);
                *(f32x4*)&sm[brow * 256 + col] = acc[vt][nt];
            }
        }
        __syncthreads();
#pragma unroll
        for (int i = 0; i < 8; ++i) {
            int fid = tid + i * 256;
            int brow = fid >> 6;              // 0..31
            int c4 = fid & 63;
            int b = pass * 32 + brow;
            int col = (c4 * 4) ^ ((b & 7) << 2);
            f32x4 vv = *(const f32x4*)&sm[brow * 256 + col];
            __builtin_nontemporal_store(vv, (f32x4*)&out[((size_t)b * HH + h) * VV + v0 + c4 * 4]);
            // CE partial over this 256-v slice (whole wave holds row b)
            float mx = fmaxf(fmaxf(vv[0], vv[1]), fmaxf(vv[2], vv[3]));
#pragma unroll
            for (int off = 32; off > 0; off >>= 1)
                mx = fmaxf(mx, __shfl_xor(mx, off));
            float se = expf(vv[0] - mx) + expf(vv[1] - mx) + expf(vv[2] - mx) + expf(vv[3] - mx);
#pragma unroll
            for (int off = 32; off > 0; off >>= 1)
                se += __shfl_xor(se, off);
            if (lane == 0) {
                pmax[(size_t)(b * HH + h) * NBLK + blk] = mx;
                psum[(size_t)(b * HH + h) * NBLK + blk] = se;
            }
        }
        __syncthreads();
    }
}

// ---------------- CE finish: reduce per-block partials -----------------------
__global__ __launch_bounds__(64) void k_ce_finish(
    const float* __restrict__ pmax, const float* __restrict__ psum,
    const float* __restrict__ logits, const float* __restrict__ act,
    const int* __restrict__ labels, float* __restrict__ nllv, float* __restrict__ cnt) {
    int p = blockIdx.x;   // b*8 + h
    int lane = threadIdx.x;
    float m = -1e30f, s = 0.f;
    for (int i = lane; i < NBLK; i += 64) {
        float m2 = pmax[(size_t)p * NBLK + i];
        float s2 = psum[(size_t)p * NBLK + i];
        float M = fmaxf(m, m2);
        s = s * expf(m - M) + s2 * expf(m2 - M);
        m = M;
    }
#pragma unroll
    for (int off = 32; off > 0; off >>= 1) {
        float m2 = __shfl_xor(m, off);
        float s2 = __shfl_xor(s, off);
        float M = fmaxf(m, m2);
        s = s * expf(m - M) + s2 * expf(m2 - M);
        m = M;
    }
    if (lane == 0) {
        int lab = labels[p];
        float lv = logits[(size_t)p * VV + lab];
        float nll = -(lv - m - logf(s));
        bool valid = (act[p] > 0.5f) && (lab != 0);
        nllv[p] = valid ? nll : 0.f;
        cnt[p]  = valid ? 1.f : 0.f;
    }
}

// ---------------- final scalar loss ------------------------------------------
__global__ void k_final_loss(const float* __restrict__ nllv, const float* __restrict__ cnt,
                             const float* __restrict__ scal, float* __restrict__ lossp) {
    __shared__ float r1[256], r2[256];
    float a = nllv[threadIdx.x] + nllv[threadIdx.x + 256];
    float c = cnt[threadIdx.x]  + cnt[threadIdx.x + 256];
    r1[threadIdx.x] = a; r2[threadIdx.x] = c; __syncthreads();
    for (int s = 128; s > 0; s >>= 1) {
        if (threadIdx.x < s) { r1[threadIdx.x] += r1[threadIdx.x + s]; r2[threadIdx.x] += r2[threadIdx.x + s]; }
        __syncthreads();
    }
    if (threadIdx.x == 0) {
        float nv = r2[0] < 1.f ? 1.f : r2[0];
        float ce = r1[0] / nv;
        lossp[0] = ce + 1.0f * scal[0] + 0.2f * scal[1] + 0.01f * scal[2] + 0.05f * scal[3];
    }
}

extern "C" void kernel_launch(void* const* d_in, const int* in_sizes, int n_in,
                              void* d_out, int out_size, void* d_ws, size_t ws_size,
                              hipStream_t stream) {
    const float* hidden = (const float*)d_in[0];
    const float* w1     = (const float*)d_in[1];
    const float* b1     = (const float*)d_in[2];
    const float* w2     = (const float*)d_in[3];
    const float* b2     = (const float*)d_in[4];
    const float* W      = (const float*)d_in[5];
    const int*   labels = (const int*)d_in[6];
    const int*   kmaxp  = (const int*)d_in[7];

    float* ws  = (float*)d_ws;
    float* out = (float*)d_out;

    _Float16* hhi = (_Float16*)(ws + OFF_HHI);
    _Float16* hlo = (_Float16*)(ws + OFF_HLO);
    float* r     = ws + OFF_R;
    float* nllv  = ws + OFF_NLL;
    float* cntv  = ws + OFF_CNT;
    float* scal  = ws + OFF_SCAL;
    float* pmax  = ws + OFF_PMAX;
    float* psum  = ws + OFF_PSUM;

    float* logits = out + OFF_LOGITS;
    float* gate   = out + OFF_GATE;
    float* activ  = out + OFF_ACT;
    float* lossp  = out + OFF_LOSS;

    // 1. hidden -> f16 hi/lo
    k_h2f16split<<<dim3(256), 256, 0, stream>>>(hidden, hhi, hlo);
    // 2. router layer 1 (MFMA, fp32-accurate via hi/lo, fused bias+GELU)
    k_router1<<<dim3(256), 64, 0, stream>>>(w1, hhi, hlo, b1, r);
    // 3. router layer 2
    k_router2<<<dim3(64), 256, 0, stream>>>(r, w2, b2, gate);
    // 4. routing / aux losses
    k_routing_aux<<<dim3(1), 64, 0, stream>>>(gate, kmaxp, activ, scal);
    // 5. big GEMM + fused logits-write + CE partials (NT, 4 blocks/CU)
    k_heads_gemm<<<dim3(NBLK * 8), 256, 0, stream>>>(W, hhi, logits, pmax, psum);
    // 6. CE finish
    k_ce_finish<<<dim3(512), 64, 0, stream>>>(pmax, psum, logits, activ, labels, nllv, cntv);
    // 7. final loss
    k_final_loss<<<dim3(1), 256, 0, stream>>>(nllv, cntv, scal, lossp);
}

// Round 12
// 295.372 us; speedup vs baseline: 1.0331x; 1.0331x over previous
//
#include <hip/hip_runtime.h>
#include <cstdint>
#include <cstddef>

#define BB 64
#define DD 1024
#define HH 8
#define VV 32000
#define H4 4096
#define BM2 512
#define BK2 16
#define NB2 63                // 62 full v-blocks + tail (v0=31488)
#define LST 516               // LDS row stride in floats (512 + 4 pad)
#define NPART 126             // NB2*2 half-row CE partials

// ws layout (float offsets)
#define OFF_HHI    0            // 64*1024 f16 = 32768 floats
#define OFF_HLO    32768        // 64*1024 f16
#define OFF_R      65536        // 64*4096 f32
#define OFF_NLL    327680       // 512
#define OFF_CNT    328192       // 512
#define OFF_SCAL   328704       // 4
#define OFF_PMAX   330000       // 512*126
#define OFF_PSUM   394512       // 512*126

// d_out layout (floats)
#define OFF_LOGITS 0
#define OFF_GATE   16384000
#define OFF_ACT    16384512
#define OFF_LOSS   16385024

typedef __attribute__((ext_vector_type(8))) _Float16 f16x8;
typedef __attribute__((ext_vector_type(4))) _Float16 f16x4;
typedef __attribute__((ext_vector_type(4))) float f32x4;

// ---------------- hidden fp32 -> f16 hi + lo ---------------------------------
__global__ void k_h2f16split(const float* __restrict__ in,
                             _Float16* __restrict__ hi_out,
                             _Float16* __restrict__ lo_out) {
    int i = blockIdx.x * 256 + threadIdx.x;   // 65536 elems
    float x = in[i];
    _Float16 hi = (_Float16)x;
    hi_out[i] = hi;
    lo_out[i] = (_Float16)(x - (float)hi);
}

// ---------------- router layer 1: r[b][j] = gelu(h @ w1^T + b1) --------------
__global__ __launch_bounds__(64) void k_router1(
    const float* __restrict__ w1, const _Float16* __restrict__ hhi,
    const _Float16* __restrict__ hlo, const float* __restrict__ b1,
    float* __restrict__ r) {
    const int j0 = blockIdx.x * 16;
    const int lane = threadIdx.x;
    const int lg = lane >> 4, lr = lane & 15;
    const float* wp = w1 + (size_t)(j0 + lr) * DD + lg * 8;

    f32x4 acc[4];
#pragma unroll
    for (int nt = 0; nt < 4; ++nt) acc[nt] = (f32x4){0.f, 0.f, 0.f, 0.f};

    for (int kc = 0; kc < DD; kc += 32) {
        float4 a0 = *(const float4*)(wp + kc);
        float4 a1 = *(const float4*)(wp + kc + 4);
        float av[8] = {a0.x, a0.y, a0.z, a0.w, a1.x, a1.y, a1.z, a1.w};
        f16x8 fahi, falo;
#pragma unroll
        for (int j = 0; j < 8; ++j) {
            _Float16 h16 = (_Float16)av[j];
            fahi[j] = h16;
            falo[j] = (_Float16)(av[j] - (float)h16);
        }
#pragma unroll
        for (int nt = 0; nt < 4; ++nt) {
            size_t boff = (size_t)(nt * 16 + lr) * DD + kc + lg * 8;
            f16x8 fbhi = *(const f16x8*)(hhi + boff);
            f16x8 fblo = *(const f16x8*)(hlo + boff);
            acc[nt] = __builtin_amdgcn_mfma_f32_16x16x32_f16(fahi, fbhi, acc[nt], 0, 0, 0);
            acc[nt] = __builtin_amdgcn_mfma_f32_16x16x32_f16(fahi, fblo, acc[nt], 0, 0, 0);
            acc[nt] = __builtin_amdgcn_mfma_f32_16x16x32_f16(falo, fbhi, acc[nt], 0, 0, 0);
        }
    }

#pragma unroll
    for (int nt = 0; nt < 4; ++nt) {
        int b = nt * 16 + lr;
        int j = j0 + lg * 4;
        float4 o;
        float* ov = (float*)&o;
#pragma unroll
        for (int q = 0; q < 4; ++q) {
            float s = acc[nt][q] + b1[j + q];
            ov[q] = 0.5f * s * (1.0f + erff(s * 0.70710678118654752f));
        }
        *(float4*)&r[(size_t)b * H4 + j] = o;
    }
}

// ---------------- router layer 2: gate[b][h] ---------------------------------
__global__ void k_router2(const float* __restrict__ r, const float* __restrict__ w2,
                          const float* __restrict__ b2, float* __restrict__ gate) {
    int b = blockIdx.x;
    int h = threadIdx.x >> 5;
    int lane = threadIdx.x & 31;
    const float* rr = r + (size_t)b * H4;
    const float* ww = w2 + (size_t)h * H4;
    float s = 0.f;
    for (int j = lane; j < H4; j += 32) s = fmaf(rr[j], ww[j], s);
    for (int off = 16; off > 0; off >>= 1) s += __shfl_down(s, off, 32);
    if (lane == 0) gate[b * HH + h] = s + b2[h];
}

// ---------------- top-k routing + BCE/LB/entropy/budget ----------------------
__global__ void k_routing_aux(const float* __restrict__ gate, const int* __restrict__ kmaxp,
                              float* __restrict__ act_out, float* __restrict__ scal) {
    __shared__ float af[64][8];
    __shared__ float bces[64], ents[64];
    int b = threadIdx.x;   // 64 threads
    float g[8];
#pragma unroll
    for (int h = 0; h < 8; ++h) g[h] = gate[b * 8 + h];
    int k = kmaxp[0]; k = k < 0 ? 0 : (k > 8 ? 8 : k);
    bool act[8] = {false, false, false, false, false, false, false, false};
    for (int s = 0; s < k; ++s) {
        int best = -1; float bv = -1e30f;
#pragma unroll
        for (int h = 0; h < 8; ++h)
            if (!act[h] && g[h] > bv) { bv = g[h]; best = h; }
        act[best] = true;
    }
    float m = -1e30f;
#pragma unroll
    for (int h = 0; h < 8; ++h) m = fmaxf(m, g[h]);
    float se = 0.f, ex[8];
#pragma unroll
    for (int h = 0; h < 8; ++h) { ex[h] = expf(g[h] - m); se += ex[h]; }
    float bce = 0.f, ent = 0.f;
#pragma unroll
    for (int h = 0; h < 8; ++h) {
        float t = act[h] ? 1.f : 0.f;
        bce += fmaxf(g[h], 0.f) - g[h] * t + log1pf(expf(-fabsf(g[h])));
        float p = ex[h] / se;
        ent -= p * logf(p + 1e-9f);
        af[b][h] = t;
        act_out[b * 8 + h] = t;
    }
    bces[b] = bce; ents[b] = ent;
    __syncthreads();
    if (b == 0) {
        float bsum = 0.f, esum = 0.f, asum = 0.f, lb = 0.f;
        for (int i = 0; i < 64; ++i) { bsum += bces[i]; esum += ents[i]; }
        for (int h = 0; h < 8; ++h) {
            float f = 0.f;
            for (int i = 0; i < 64; ++i) f += af[i][h];
            asum += f;
            float fr = f / 64.f - 0.125f;
            lb += fr * fr;
        }
        scal[0] = bsum / 512.f;   // bce mean
        scal[1] = lb;             // load balance
        scal[2] = esum / 64.f;    // entropy mean
        scal[3] = asum / 512.f;   // budget
    }
}

// ---------------- big GEMM: MFMA 16x16x16 f16, BM=512 (2KB spans), NT --------
// R9 loop skeleton (dbuf, NT gll, drain+barrier per chunk) with BM=512/BK=16:
// every DRAM touch is a 2KB contiguous row (vs 1KB before) — span-length probe.
// LDS [16][516] f32 x2 (pad => A-reads 2-way max, no swizzle). Per wave:
// 128 v x 64 b via 8vt x 4nt mfma_f32_16x16x16_f16 (same kappa map both ops).
// Tail block v0=31488 (exact fit, overlap-stores benign, CE per half-row).
__global__ __launch_bounds__(256, 2) void k_heads_gemm(
    const float* __restrict__ W, const _Float16* __restrict__ hA,
    float* __restrict__ out, float* __restrict__ pmax, float* __restrict__ psum) {
    __shared__ __align__(16) float ldsA[2][BK2 * LST];   // 2 x 33 KB
    const int bid = blockIdx.x;
    const int h   = bid & 7;
    const int blk = bid >> 3;
    const int v0  = (blk == NB2 - 1) ? (VV - BM2) : blk * BM2;
    const bool tail = (blk == NB2 - 1);
    const int tid = threadIdx.x;
    const int wv = tid >> 6, lane = tid & 63;
    const int lg = lane >> 4, lr = lane & 15;

    const float* wbase = W + (size_t)h * DD * VV + v0;

#define STAGE(kc_, buf_)                                                        \
    {                                                                           \
        _Pragma("unroll")                                                       \
        for (int i_ = 0; i_ < 4; ++i_) {                                        \
            int r_ = wv + 4 * i_;                                               \
            _Pragma("unroll")                                                   \
            for (int hh_ = 0; hh_ < 2; ++hh_) {                                 \
                const float* src_ = wbase + (size_t)((kc_) * BK2 + r_) * VV     \
                                    + hh_ * 256 + lane * 4;                     \
                __builtin_amdgcn_global_load_lds(                               \
                    (const __attribute__((address_space(1))) unsigned int*)src_,\
                    (__attribute__((address_space(3))) unsigned int*)           \
                        &ldsA[buf_][r_ * LST + hh_ * 256],                      \
                    16, 0, 2 /* CPol NT */);                                    \
            }                                                                   \
        }                                                                       \
    }

    f32x4 acc[8][4];
#pragma unroll
    for (int vt = 0; vt < 8; ++vt)
#pragma unroll
        for (int nt = 0; nt < 4; ++nt) acc[vt][nt] = (f32x4){0.f, 0.f, 0.f, 0.f};

    STAGE(0, 0);
    asm volatile("s_waitcnt vmcnt(0)" ::: "memory");
    __syncthreads();

    for (int kc = 0; kc < DD / BK2; ++kc) {   // 64 chunks
        const int cur = kc & 1;

        // B-frags FIRST (4 x 8B, L2-resident)
        f16x4 fb[4];
#pragma unroll
        for (int nt = 0; nt < 4; ++nt)
            fb[nt] = *(const f16x4*)(hA + (size_t)(nt * 16 + lr) * DD + kc * BK2 + lg * 4);

        if (kc < DD / BK2 - 1) STAGE(kc + 1, cur ^ 1);

        // A-frags from LDS (padded stride => 2-way max) + MFMA
#pragma unroll
        for (int vt = 0; vt < 8; ++vt) {
            const int col = wv * 128 + vt * 16 + lr;
            f16x4 fa;
#pragma unroll
            for (int j = 0; j < 4; ++j)
                fa[j] = (_Float16)ldsA[cur][(lg * 4 + j) * LST + col];
#pragma unroll
            for (int nt = 0; nt < 4; ++nt)
                acc[vt][nt] = __builtin_amdgcn_mfma_f32_16x16x16f16(fa, fb[nt], acc[vt][nt], 0, 0, 0);
        }

        asm volatile("s_waitcnt vmcnt(0)" ::: "memory");
        __syncthreads();
    }

    // ---- epilogue: 2 passes through LDS [32][516] -> 2KB row writes + CE ----
    float* sm = &ldsA[0][0];
#pragma unroll
    for (int pass = 0; pass < 2; ++pass) {
#pragma unroll
        for (int nt2 = 0; nt2 < 2; ++nt2) {
            int nt = pass * 2 + nt2;
            int b = nt * 16 + lr;
            int brow = nt2 * 16 + lr;
#pragma unroll
            for (int vt = 0; vt < 8; ++vt) {
                int vcol = wv * 128 + vt * 16 + lg * 4;
                int col = vcol ^ ((b & 7) << 2);
                *(f32x4*)&sm[brow * LST + col] = acc[vt][nt];
            }
        }
        __syncthreads();
#pragma unroll
        for (int i = 0; i < 16; ++i) {
            int fid = tid + i * 256;          // 0..4095
            int brow = fid >> 7;              // 0..31
            int c4 = fid & 127;               // 0..127 (float4 index in 512 row)
            int b = pass * 32 + brow;
            int col = (c4 * 4) ^ ((b & 7) << 2);
            f32x4 vv = *(const f32x4*)&sm[brow * LST + col];
            __builtin_nontemporal_store(vv, (f32x4*)&out[((size_t)b * HH + h) * VV + v0 + c4 * 4]);
            // CE partial per half-row: lanes of a wave share (brow, half)
            int half = (wv & 1);              // c4 = half*64 + lane
            if (!(tail && half == 0)) {
                float mx = fmaxf(fmaxf(vv[0], vv[1]), fmaxf(vv[2], vv[3]));
#pragma unroll
                for (int off = 32; off > 0; off >>= 1)
                    mx = fmaxf(mx, __shfl_xor(mx, off));
                float se = expf(vv[0] - mx) + expf(vv[1] - mx) + expf(vv[2] - mx) + expf(vv[3] - mx);
#pragma unroll
                for (int off = 32; off > 0; off >>= 1)
                    se += __shfl_xor(se, off);
                if (lane == 0) {
                    pmax[(size_t)(b * HH + h) * NPART + blk * 2 + half] = mx;
                    psum[(size_t)(b * HH + h) * NPART + blk * 2 + half] = se;
                }
            }
        }
        __syncthreads();
    }
#undef STAGE
}

// ---------------- CE finish: reduce per-(block,half) partials ----------------
__global__ __launch_bounds__(64) void k_ce_finish(
    const float* __restrict__ pmax, const float* __restrict__ psum,
    const float* __restrict__ logits, const float* __restrict__ act,
    const int* __restrict__ labels, float* __restrict__ nllv, float* __restrict__ cnt) {
    int p = blockIdx.x;   // b*8 + h
    int lane = threadIdx.x;
    float m = -1e30f, s = 0.f;
    for (int i = lane; i < NPART; i += 64) {
        if (i == (NB2 - 1) * 2) continue;   // tail half0: never written
        float m2 = pmax[(size_t)p * NPART + i];
        float s2 = psum[(size_t)p * NPART + i];
        float M = fmaxf(m, m2);
        s = s * expf(m - M) + s2 * expf(m2 - M);
        m = M;
    }
#pragma unroll
    for (int off = 32; off > 0; off >>= 1) {
        float m2 = __shfl_xor(m, off);
        float s2 = __shfl_xor(s, off);
        float M = fmaxf(m, m2);
        s = s * expf(m - M) + s2 * expf(m2 - M);
        m = M;
    }
    if (lane == 0) {
        int lab = labels[p];
        float lv = logits[(size_t)p * VV + lab];
        float nll = -(lv - m - logf(s));
        bool valid = (act[p] > 0.5f) && (lab != 0);
        nllv[p] = valid ? nll : 0.f;
        cnt[p]  = valid ? 1.f : 0.f;
    }
}

// ---------------- final scalar loss ------------------------------------------
__global__ void k_final_loss(const float* __restrict__ nllv, const float* __restrict__ cnt,
                             const float* __restrict__ scal, float* __restrict__ lossp) {
    __shared__ float r1[256], r2[256];
    float a = nllv[threadIdx.x] + nllv[threadIdx.x + 256];
    float c = cnt[threadIdx.x]  + cnt[threadIdx.x + 256];
    r1[threadIdx.x] = a; r2[threadIdx.x] = c; __syncthreads();
    for (int s = 128; s > 0; s >>= 1) {
        if (threadIdx.x < s) { r1[threadIdx.x] += r1[threadIdx.x + s]; r2[threadIdx.x] += r2[threadIdx.x + s]; }
        __syncthreads();
    }
    if (threadIdx.x == 0) {
        float nv = r2[0] < 1.f ? 1.f : r2[0];
        float ce = r1[0] / nv;
        lossp[0] = ce + 1.0f * scal[0] + 0.2f * scal[1] + 0.01f * scal[2] + 0.05f * scal[3];
    }
}

extern "C" void kernel_launch(void* const* d_in, const int* in_sizes, int n_in,
                              void* d_out, int out_size, void* d_ws, size_t ws_size,
                              hipStream_t stream) {
    const float* hidden = (const float*)d_in[0];
    const float* w1     = (const float*)d_in[1];
    const float* b1     = (const float*)d_in[2];
    const float* w2     = (const float*)d_in[3];
    const float* b2     = (const float*)d_in[4];
    const float* W      = (const float*)d_in[5];
    const int*   labels = (const int*)d_in[6];
    const int*   kmaxp  = (const int*)d_in[7];

    float* ws  = (float*)d_ws;
    float* out = (float*)d_out;

    _Float16* hhi = (_Float16*)(ws + OFF_HHI);
    _Float16* hlo = (_Float16*)(ws + OFF_HLO);
    float* r     = ws + OFF_R;
    float* nllv  = ws + OFF_NLL;
    float* cntv  = ws + OFF_CNT;
    float* scal  = ws + OFF_SCAL;
    float* pmax  = ws + OFF_PMAX;
    float* psum  = ws + OFF_PSUM;

    float* logits = out + OFF_LOGITS;
    float* gate   = out + OFF_GATE;
    float* activ  = out + OFF_ACT;
    float* lossp  = out + OFF_LOSS;

    // 1. hidden -> f16 hi/lo
    k_h2f16split<<<dim3(256), 256, 0, stream>>>(hidden, hhi, hlo);
    // 2. router layer 1 (MFMA, fp32-accurate via hi/lo, fused bias+GELU)
    k_router1<<<dim3(256), 64, 0, stream>>>(w1, hhi, hlo, b1, r);
    // 3. router layer 2
    k_router2<<<dim3(64), 256, 0, stream>>>(r, w2, b2, gate);
    // 4. routing / aux losses
    k_routing_aux<<<dim3(1), 64, 0, stream>>>(gate, kmaxp, activ, scal);
    // 5. big GEMM + fused logits-write + CE partials (2KB spans, NT)
    k_heads_gemm<<<dim3(NB2 * 8), 256, 0, stream>>>(W, hhi, logits, pmax, psum);
    // 6. CE finish
    k_ce_finish<<<dim3(512), 64, 0, stream>>>(pmax, psum, logits, activ, labels, nllv, cntv);
    // 7. final loss
    k_final_loss<<<dim3(1), 256, 0, stream>>>(nllv, cntv, scal, lossp);
}